// Round 12
// baseline (1190.412 us; speedup 1.0000x reference)
//
#include <hip/hip_runtime.h>
#include <hip/hip_bf16.h>

// Problem constants (from reference setup_inputs)
#define KK   27
#define MM   80000
#define NN   200000
#define INC  64
#define OUTC 128
#define RIN  48
#define ROUT 96

// output-row slices: 2500 slices x 80 rows; LDS accumulator 80x96 fp32
#define SLICE   80
#define NSLICE  (NN / SLICE)          // 2500 (exact)
#define NKEY    (NSLICE * KK)         // 67500 buckets (slice-major, k-minor)
#define PADR    (ROUT + 1)            // 97: LDS row pad -> conflict-free ds adds

// counting-sort blocking: 4096 entries per (k,block)
#define HEPB    4096
#define HBLK    ((MM + HEPB - 1) / HEPB)   // 20
#define NC      (NKEY * HBLK)         // 1,350,000 flat counts
#define ETOT    (KK * MM)             // 2,160,000

// flat-scan geometry
#define SCHUNK  1024
#define NCB     ((NC + SCHUNK - 1) / SCHUNK)   // 1319
#define MIDW    6                     // 256*6 = 1536 >= NCB

typedef __attribute__((ext_vector_type(8))) short bf16x8;  // 8 bf16 = 4 VGPR
typedef __attribute__((ext_vector_type(4))) float f32x4;

// ---------------------------------------------------------------------------
// Fallback: single-pass atomic scatter (R1 kernel, known-good, ~1.66 ms)
// ---------------------------------------------------------------------------
#define FB_BLOCKS_PER_K 200
#define FB_ENTRIES_PER_BLOCK ((MM + FB_BLOCKS_PER_K - 1) / FB_BLOCKS_PER_K)

__global__ __launch_bounds__(192)
void sparse_conv_scatter(const float* __restrict__ feat,
                         const float* __restrict__ w,
                         const int* __restrict__ imap,
                         const int* __restrict__ omap,
                         float* __restrict__ out)
{
    __shared__ float wlds[RIN * ROUT];
    const int k = blockIdx.y;
    const float* wk = w + (size_t)k * INC * OUTC;
    for (int idx = threadIdx.x; idx < RIN * ROUT; idx += 192) {
        int i = idx / ROUT;
        int o = idx - i * ROUT;
        wlds[idx] = wk[i * OUTC + o];
    }
    __syncthreads();

    const int sub = threadIdx.x / 96;
    const int oc  = threadIdx.x % 96;
    const int m0 = blockIdx.x * FB_ENTRIES_PER_BLOCK;
    const int m1 = min(m0 + FB_ENTRIES_PER_BLOCK, MM);
    const int* imk = imap + (size_t)k * MM;
    const int* omk = omap + (size_t)k * MM;

    for (int m = m0 + sub; m < m1; m += 2) {
        const int fin  = imk[m];
        const int fout = omk[m];
        const float4* f4 = (const float4*)(feat + (size_t)fin * RIN);
        float acc = 0.f;
        #pragma unroll
        for (int i4 = 0; i4 < RIN / 4; ++i4) {
            float4 v = f4[i4];
            acc += v.x * wlds[(i4 * 4 + 0) * ROUT + oc];
            acc += v.y * wlds[(i4 * 4 + 1) * ROUT + oc];
            acc += v.z * wlds[(i4 * 4 + 2) * ROUT + oc];
            acc += v.w * wlds[(i4 * 4 + 3) * ROUT + oc];
        }
        atomicAdd(&out[(size_t)fout * ROUT + oc], acc);
    }
}

// ---------------------------------------------------------------------------
// Precompute: features -> bf16, weights -> MFMA B-fragment pack
// ---------------------------------------------------------------------------
__global__ __launch_bounds__(256)
void feat_to_bf16(const float* __restrict__ f, __hip_bfloat16* __restrict__ fb)
{
    const size_t i = (size_t)blockIdx.x * 256 + threadIdx.x;   // one per 8 elems
    if (i >= (size_t)NN * RIN / 8) return;
    const float4* p = (const float4*)(f + i * 8);
    float4 a = p[0], b = p[1];
    union { __hip_bfloat16 h[8]; uint4 v; } o;
    o.h[0] = __float2bfloat16(a.x);
    o.h[1] = __float2bfloat16(a.y);
    o.h[2] = __float2bfloat16(a.z);
    o.h[3] = __float2bfloat16(a.w);
    o.h[4] = __float2bfloat16(b.x);
    o.h[5] = __float2bfloat16(b.y);
    o.h[6] = __float2bfloat16(b.z);
    o.h[7] = __float2bfloat16(b.w);
    ((uint4*)fb)[i] = o.v;
}

// wpack: frag f = oct*2 + ktile of kernel k at ((k*12 + f)*64 + lane)*16 bytes
__global__ __launch_bounds__(64)
void build_wpack(const float* __restrict__ w, __hip_bfloat16* __restrict__ wp)
{
    const int b = blockIdx.x;          // k*12 + f
    const int k = b / 12;
    const int f = b % 12;
    const int oct = f / 2, ktile = f % 2;
    const int lane = threadIdx.x;
    const int oc    = oct * 16 + (lane & 15);
    const int kbase = ktile * 32 + (lane >> 4) * 8;
    union { __hip_bfloat16 h[8]; uint4 v; } o;
    #pragma unroll
    for (int j = 0; j < 8; ++j) {
        int ki = kbase + j;
        float val = (ki < RIN) ? w[(size_t)k * INC * OUTC + (size_t)ki * OUTC + oc] : 0.f;
        o.h[j] = __float2bfloat16(val);
    }
    ((uint4*)wp)[(size_t)b * 64 + lane] = o.v;
}

// ---------------------------------------------------------------------------
// Counting sort, pass 1: per-(k,block) LDS histogram over slices.
// C[(s*KK + k)*HBLK + blk] = count. NO global atomics.
// ---------------------------------------------------------------------------
__global__ __launch_bounds__(256)
void hist_pass(const int* __restrict__ omap, int* __restrict__ C)
{
    __shared__ int h[NSLICE];
    const int k = blockIdx.y;
    const int blk = blockIdx.x;
    for (int i = threadIdx.x; i < NSLICE; i += 256) h[i] = 0;
    __syncthreads();

    #pragma unroll
    for (int it = 0; it < HEPB / 256; ++it) {
        const int m = blk * HEPB + it * 256 + threadIdx.x;
        if (m < MM) {
            const int r = omap[(size_t)k * MM + m];
            atomicAdd(&h[r / SLICE], 1);     // LDS atomic
        }
    }
    __syncthreads();
    for (int i = threadIdx.x; i < NSLICE; i += 256)
        C[((size_t)i * KK + k) * HBLK + blk] = h[i];
}

// ---------------------------------------------------------------------------
// Flat exclusive scan of C[NC] (3 kernels)
// ---------------------------------------------------------------------------
__global__ __launch_bounds__(256)
void scan_part2(const int* __restrict__ C, int* __restrict__ S)
{
    __shared__ int sh[256];
    const int t = threadIdx.x;
    const int base = blockIdx.x * SCHUNK + t * 4;
    int s = 0;
    #pragma unroll
    for (int j = 0; j < 4; ++j)
        if (base + j < NC) s += C[base + j];
    sh[t] = s;
    __syncthreads();
    for (int off = 128; off > 0; off >>= 1) {
        if (t < off) sh[t] += sh[t + off];
        __syncthreads();
    }
    if (t == 0) S[blockIdx.x] = sh[0];
}

__global__ __launch_bounds__(256)
void scan_mid(int* __restrict__ S)
{
    __shared__ int sh[256];
    const int t = threadIdx.x;
    int v[MIDW];
    int tot = 0;
    #pragma unroll
    for (int j = 0; j < MIDW; ++j) {
        const int idx = t * MIDW + j;
        v[j] = (idx < NCB) ? S[idx] : 0;
        tot += v[j];
    }
    sh[t] = tot;
    __syncthreads();
    for (int off = 1; off < 256; off <<= 1) {
        int x = (t >= off) ? sh[t - off] : 0;
        __syncthreads();
        sh[t] += x;
        __syncthreads();
    }
    int run = sh[t] - tot;    // exclusive base
    #pragma unroll
    for (int j = 0; j < MIDW; ++j) {
        const int idx = t * MIDW + j;
        if (idx < NCB) { const int tv = v[j]; S[idx] = run; run += tv; }
    }
}

__global__ __launch_bounds__(256)
void scan_final2(int* __restrict__ C, const int* __restrict__ S)
{
    __shared__ int sh[256];
    const int t = threadIdx.x;
    const int base = blockIdx.x * SCHUNK + t * 4;
    int v[4];
    int s = 0;
    #pragma unroll
    for (int j = 0; j < 4; ++j) {
        v[j] = (base + j < NC) ? C[base + j] : 0;
        s += v[j];
    }
    sh[t] = s;
    __syncthreads();
    for (int off = 1; off < 256; off <<= 1) {
        int x = (t >= off) ? sh[t - off] : 0;
        __syncthreads();
        sh[t] += x;
        __syncthreads();
    }
    int run = sh[t] - s + S[blockIdx.x];
    #pragma unroll
    for (int j = 0; j < 4; ++j) {
        if (base + j < NC) { C[base + j] = run; run += v[j]; }
    }
}

// ---------------------------------------------------------------------------
// Counting sort, pass 2: scatter entries to elist. Cross-block base from the
// scanned C; within-block rank from LDS atomics (order-free bijection).
// elist[slot] = fin | (localrow << 18)
// ---------------------------------------------------------------------------
__global__ __launch_bounds__(256)
void write_elist(const int* __restrict__ omap,
                 const int* __restrict__ imap,
                 const int* __restrict__ Cs,
                 unsigned* __restrict__ elist)
{
    __shared__ int run[NSLICE];
    const int k = blockIdx.y;
    const int blk = blockIdx.x;
    for (int i = threadIdx.x; i < NSLICE; i += 256) run[i] = 0;
    __syncthreads();

    #pragma unroll
    for (int it = 0; it < HEPB / 256; ++it) {
        const int m = blk * HEPB + it * 256 + threadIdx.x;
        if (m < MM) {
            const size_t e = (size_t)k * MM + m;
            const int r = omap[e];
            const int s = r / SLICE;
            const int lr = r - s * SLICE;
            const int rank = atomicAdd(&run[s], 1);   // LDS atomic
            const int base = Cs[((size_t)s * KK + k) * HBLK + blk];
            elist[base + rank] = (unsigned)imap[e] | ((unsigned)lr << 18);
        }
    }
}

// ---------------------------------------------------------------------------
// Fused compute: one block per slice. Per k-run: MFMA 16-entry x 96-oc tiles,
// scatter-add results into the LDS slice accumulator, then write the slice
// to `out` once, coalesced. Waves own k = wid, wid+4, ...
// ---------------------------------------------------------------------------
__global__ __launch_bounds__(256)
void fused_slice(const __hip_bfloat16* __restrict__ fb,
                 const __hip_bfloat16* __restrict__ wp,
                 const unsigned* __restrict__ elist,
                 const int* __restrict__ Cs,
                 float* __restrict__ out)
{
    __shared__ float acc[SLICE * PADR];    // 80*97*4 = 31040 B
    const int s = blockIdx.x;
    const int wid  = threadIdx.x >> 6;
    const int lane = threadIdx.x & 63;
    const int lo = lane & 15, hi = lane >> 4;

    for (int i = threadIdx.x; i < SLICE * PADR; i += 256) acc[i] = 0.f;
    __syncthreads();

    for (int k = wid; k < KK; k += 4) {
        const size_t key = (size_t)s * KK + k;
        const int base = Cs[key * HBLK];
        const int end  = (key + 1 < NKEY) ? Cs[(key + 1) * HBLK] : ETOT;
        const int n = end - base;
        if (n <= 0) continue;

        bf16x8 B[12];
        #pragma unroll
        for (int f = 0; f < 12; ++f)
            B[f] = *reinterpret_cast<const bf16x8*>(
                (const char*)wp + (((size_t)k * 12 + f) * 64 + lane) * 16);

        const int ntiles = (n + 15) >> 4;
        for (int t = 0; t < ntiles; ++t) {
            // A-operand: entry (t*16 + lo)'s feature row
            const int ea = base + t * 16 + lo;
            const unsigned ela = (ea < end) ? elist[ea] : 0u;
            const int row = (int)(ela & 0x3FFFFu);
            const bf16x8 A0 = *reinterpret_cast<const bf16x8*>(
                (const char*)fb + (size_t)row * 96 + hi * 16);
            const bf16x8 A1 = *reinterpret_cast<const bf16x8*>(
                (const char*)fb + (size_t)row * 96 + 64 + hi * 16);

            // local output rows for this lane's 4 accumulator entries
            int lr[4]; bool vl[4];
            #pragma unroll
            for (int j = 0; j < 4; ++j) {
                const int ej = base + t * 16 + hi * 4 + j;
                vl[j] = (ej < end);
                const unsigned el = vl[j] ? elist[ej] : 0u;
                lr[j] = (int)(el >> 18);
            }

            #pragma unroll
            for (int oct = 0; oct < 6; ++oct) {
                f32x4 a = {0.f, 0.f, 0.f, 0.f};
                a = __builtin_amdgcn_mfma_f32_16x16x32_bf16(A0, B[oct * 2 + 0], a, 0, 0, 0);
                a = __builtin_amdgcn_mfma_f32_16x16x32_bf16(A1, B[oct * 2 + 1], a, 0, 0, 0);
                const int c = oct * 16 + lo;
                #pragma unroll
                for (int j = 0; j < 4; ++j)
                    if (vl[j]) atomicAdd(&acc[lr[j] * PADR + c], a[j]);
            }
        }
    }
    __syncthreads();

    // coalesced slice write: out rows are contiguous
    float* os = out + (size_t)s * SLICE * ROUT;
    for (int i = threadIdx.x; i < SLICE * ROUT; i += 256) {
        const int lr = i / ROUT;
        const int c  = i - lr * ROUT;
        os[i] = acc[lr * PADR + c];
    }
}

// ---------------------------------------------------------------------------
extern "C" void kernel_launch(void* const* d_in, const int* in_sizes, int n_in,
                              void* d_out, int out_size, void* d_ws, size_t ws_size,
                              hipStream_t stream)
{
    const float* features = (const float*)d_in[0];
    const float* kernel_w = (const float*)d_in[1];
    const int*   in_map   = (const int*)d_in[2];
    const int*   out_map  = (const int*)d_in[3];
    float*       out      = (float*)d_out;

    // workspace layout (16B-aligned)
    const size_t off_C     = 0;                                   // NC ints
    const size_t off_S     = off_C + (((size_t)NC * 4 + 255) & ~255ul);       // NCB ints
    const size_t off_fb    = off_S + (((size_t)NCB * 4 + 255) & ~255ul);      // NN*RIN bf16
    const size_t off_wp    = off_fb + (size_t)NN * RIN * 2;       // KK*12*64*16 B
    const size_t off_elist = off_wp + (size_t)KK * 12 * 64 * 16;  // (ETOT+16) uints
    const size_t total_ws  = off_elist + ((size_t)ETOT + 16) * 4;

    if (ws_size < total_ws) {
        hipMemsetAsync(d_out, 0, (size_t)out_size * sizeof(float), stream);
        dim3 grid(FB_BLOCKS_PER_K, KK);
        sparse_conv_scatter<<<grid, 192, 0, stream>>>(features, kernel_w, in_map, out_map, out);
        return;
    }

    char* ws = (char*)d_ws;
    int*      C     = (int*)(ws + off_C);
    int*      S     = (int*)(ws + off_S);
    __hip_bfloat16* fb = (__hip_bfloat16*)(ws + off_fb);
    __hip_bfloat16* wp = (__hip_bfloat16*)(ws + off_wp);
    unsigned* elist = (unsigned*)(ws + off_elist);

    // precompute (no memsets needed anywhere: C fully written by hist_pass,
    // out fully written by fused_slice)
    feat_to_bf16<<<(NN * RIN / 8 + 255) / 256, 256, 0, stream>>>(features, fb);
    build_wpack<<<KK * 12, 64, 0, stream>>>(kernel_w, wp);

    // counting sort by (slice, k): histogram -> flat exclusive scan -> scatter
    {
        dim3 gh(HBLK, KK);
        hist_pass<<<gh, 256, 0, stream>>>(out_map, C);
    }
    scan_part2<<<NCB, 256, 0, stream>>>(C, S);
    scan_mid<<<1, 256, 0, stream>>>(S);
    scan_final2<<<NCB, 256, 0, stream>>>(C, S);
    {
        dim3 gw(HBLK, KK);
        write_elist<<<gw, 256, 0, stream>>>(out_map, in_map, C, elist);
    }

    // fused MFMA + LDS scatter-reduce + coalesced out write
    fused_slice<<<NSLICE, 256, 0, stream>>>(fb, wp, elist, C, out);
}